// Round 15
// baseline (55.356 us; speedup 1.0000x reference)
//
#include <hip/hip_runtime.h>
#include <math.h>

// Problem constants: B=4, C=128, H=W=96, E=4, C8=16, scale=2 (baked in)
#define Bn 4
#define Cc 128
#define Hh 96
#define Ww 96
#define H2c 192
#define W2c 192
#define HW (Hh*Ww)
#define HW2 (H2c*W2c)

// Workspace: floats [0,16) = per-class taps {tx,ty,Dx,Dy};
//            ushort Mw at float-offset 16: M[cls][c_out][128] (We*Wc + I, bf16)
#define TAP_OFF 0
#define M_OFF 16

typedef float  f32x4  __attribute__((ext_vector_type(4)));
typedef short  s16x8  __attribute__((ext_vector_type(8)));

__device__ __forceinline__ unsigned f2bf(float f) {
    unsigned u = __float_as_uint(f);
    return (u + 0x7FFFu + ((u >> 16) & 1u)) >> 16;   // RNE to bf16
}

// global -> LDS DMA, 16B per lane. LDS dest = wave-uniform base + lane*16.
__device__ __forceinline__ void gload_lds16(const float* g, float* l) {
    __builtin_amdgcn_global_load_lds(
        (const __attribute__((address_space(1))) unsigned int*)g,
        (__attribute__((address_space(3))) unsigned int*)l, 16, 0, 0);
}

// ---------------------------------------------------------------------------
// K1 (fused): per-class MLP -> taps AND M[cls] = We_mix*Wc_mix + I from
// GLOBAL wcomp/wexp. 64 blocks x 256 threads; block (cls, chunk) owns
// M rows [chunk*8, chunk*8+8). (Algebra re-verified vs reference layouts.)
__global__ __launch_bounds__(256) void k1_prep(
    const float* __restrict__ wcomp, const float* __restrict__ wexp,
    const float* __restrict__ bw1, const float* __restrict__ bb1,
    const float* __restrict__ bw2, const float* __restrict__ bb2,
    const float* __restrict__ rw,  const float* __restrict__ rb,
    const float* __restrict__ ow,  const float* __restrict__ ob,
    float* __restrict__ ws, unsigned short* __restrict__ Mw)
{
    __shared__ float e1[64], e2[64], rr4[4], of2[2];
    const int tid   = threadIdx.x;
    const int cls   = blockIdx.x >> 4;
    const int chunk = blockIdx.x & 15;
    const float chv = (cls & 2) ? 0.25f : -0.25f;
    const float cwv = (cls & 1) ? 0.25f : -0.25f;

    if (tid < 64) {
        float h = bw1[tid*3+0]*0.5f + bw1[tid*3+1]*chv + bw1[tid*3+2]*cwv + bb1[tid];
        e1[tid] = fmaxf(h, 0.f);
    }
    __syncthreads();
    if (tid < 64) {
        float s = bb2[tid];
        for (int i = 0; i < 64; ++i) s += bw2[tid*64+i]*e1[i];
        e2[tid] = fmaxf(s, 0.f);
    }
    __syncthreads();
    if (tid < 6) {
        if (tid < 4) {
            float s = rb[tid];
            for (int i = 0; i < 64; ++i) s += rw[tid*64+i]*e2[i];
            rr4[tid] = 1.f/(1.f+expf(-s));
        } else {
            const int d = tid - 4;
            float s = ob[d];
            for (int i = 0; i < 64; ++i) s += ow[d*64+i]*e2[i];
            of2[d] = s;
        }
    }
    __syncthreads();
    const float r0 = rr4[0], r1 = rr4[1], r2 = rr4[2], r3 = rr4[3];

    if (chunk == 0 && tid == 0) {
        const float fx = cwv + of2[0];
        const float fy = chv + of2[1];
        const float Dx = floorf(fx), Dy = floorf(fy);
        ws[TAP_OFF + cls*4 + 0] = fx - Dx;
        ws[TAP_OFF + cls*4 + 1] = fy - Dy;
        ws[TAP_OFF + cls*4 + 2] = Dx;
        ws[TAP_OFF + cls*4 + 3] = Dy;
    }

    // M slice: thread -> (co, ci0..ci0+3). wexp[e][c][o] flat e*2048+c*16+o;
    // wcomp[e][o][c] flat e*2048+o*128+c.
    const int co  = chunk*8 + (tid >> 5);
    const int ci0 = (tid & 31) * 4;
    const float* weB = wexp + co*16;
    float wem[16];
    #pragma unroll
    for (int o = 0; o < 16; ++o)
        wem[o] = r0*weB[o] + r1*weB[2048+o] + r2*weB[4096+o] + r3*weB[6144+o];
    float m[4];
    #pragma unroll
    for (int q = 0; q < 4; ++q) {
        const int ci = ci0 + q;
        const float* wcB = wcomp + ci;
        float s = 0.f;
        #pragma unroll
        for (int o = 0; o < 16; ++o) {
            const float wcm = r0*wcB[o*128]        + r1*wcB[2048 + o*128]
                            + r2*wcB[4096 + o*128] + r3*wcB[6144 + o*128];
            s += wem[o]*wcm;
        }
        if (co == ci) s += 1.f;      // residual identity folded in
        m[q] = s;
    }
    uint2 v;
    v.x = f2bf(m[0]) | (f2bf(m[1]) << 16);
    v.y = f2bf(m[2]) | (f2bf(m[3]) << 16);
    *reinterpret_cast<uint2*>(Mw + (size_t)cls*16384 + co*128 + ci0) = v;
}

// Edge remap (verified rounds 1-13).
__device__ __forceinline__ void remap_axis(int c0, int last, float w0, float w1,
                                           int& base, float& a0, float& a1)
{
    base = min(max(c0, 0), last - 1);
    if (c0 >= 0 && c0 < last) { a0 = w0;  a1 = w1;  }
    else if (c0 == -1)        { a0 = w1;  a1 = 0.f; }
    else if (c0 == last)      { a0 = 0.f; a1 = w0;  }
    else                      { a0 = 0.f; a1 = 0.f; }
}

// ---------------------------------------------------------------------------
// K2: TWO same-class vertically-adjacent tiles per block, conservative sync.
// 1152 blocks x 256 threads. Per tile: r12's DMA pipeline VERBATIM (8 chunks,
// 2 in flight, counted vmcnt, internal WAR fences) -> __syncthreads() ->
// 32 MFMA + scalar-dword stores -> __syncthreads() -> next tile. All setup
// (M frags, taps, x-remap, staging lanes) computed once for both tiles.
__global__ __launch_bounds__(256) void k2_mfma(
    const float* __restrict__ x, const float* __restrict__ wsr,
    const unsigned short* __restrict__ Mw, float* __restrict__ out)
{
    __shared__ __align__(16) unsigned short lF[64*128];   // 16 KB fea tile (swizzled)
    __shared__ __align__(16) float lWin[4*2*512];         // 16 KB: [wave][buf][512]

    const int tid = threadIdx.x;
    const int xl  = tid & 63;
    const int grp = tid >> 6;

    // XCD-paired swizzle: 1152 = 8 XCDs * 144; the 4 classes of a tile-pair
    // are consecutive on ONE XCD (stride-2 stores merge, x rows shared).
    const int n = blockIdx.x;
    const int w = (n & 7)*144 + (n >> 3);
    const int cls  = w & 3;
    const int px_  = cls & 1, py = (cls >> 1) & 1;
    const int rest = w >> 2;          // 0..287
    const int b    = rest / 72;
    const int pr72 = rest % 72;
    const int jt = pr72 / 3, xs = pr72 % 3;
    const int j0A = jt*4, j0B = jt*4 + 2;   // two vertically-adjacent tiles
    const int i0  = xs*32;

    // ---- A fragments: M rows for this wave's 32 out-channels (shared) ----
    const unsigned short* Mc = Mw + (size_t)cls*16384;
    const int lo = xl & 15, hi = xl >> 4;
    s16x8 a[2][4];
    #pragma unroll
    for (int t = 0; t < 2; ++t)
        #pragma unroll
        for (int kk = 0; kk < 4; ++kk)
            a[t][kk] = *reinterpret_cast<const s16x8*>(
                Mc + (32*grp + 16*t + lo)*128 + kk*32 + hi*8);

    // ---- taps & shared x-axis setup ----
    const int pr = xl >> 5, pc = xl & 31;
    const int i  = i0 + pc;
    const float tx = wsr[TAP_OFF + cls*4 + 0];
    const float ty = wsr[TAP_OFF + cls*4 + 1];
    const int   Dx = (int)wsr[TAP_OFF + cls*4 + 2];
    const int   Dy = (int)wsr[TAP_OFF + cls*4 + 3];

    int basex; float ax0, ax1;
    remap_axis(i + Dx, Ww - 1, 1.f - tx, tx, basex, ax0, ax1);
    int baseyA, baseyB; float ay0A, ay1A, ay0B, ay1B;
    remap_axis(j0A + pr + Dy, Hh - 1, 1.f - ty, ty, baseyA, ay0A, ay1A);
    remap_axis(j0B + pr + Dy, Hh - 1, 1.f - ty, ty, baseyB, ay0B, ay1B);
    const float w00A = ay0A*ax0, w01A = ay0A*ax1, w10A = ay1A*ax0, w11A = ay1A*ax1;
    const float w00B = ay0B*ax0, w01B = ay0B*ax1, w10B = ay1B*ax0, w11B = ay1B*ax1;

    const int cs0  = min(max((i0 + Dx) & ~3, 0), Ww - 40);
    const int cidx = basex - cs0;
    const int ro0  = pr*40 + cidx, ro1 = ro0 + 40;

    // staging lane assignment (verified r11/r12)
    const int sl = xl & 31, s2 = min(sl, 29);
    const int lr = s2 / 10, lq = s2 - lr*10;
    const int chsub = xl >> 5;
    const int lrowA = min(max(j0A + Dy + lr, 0), Hh - 1);
    const int lrowB = min(max(j0B + Dy + lr, 0), Hh - 1);
    const float* gsrcA = x + (size_t)b*Cc*HW + (size_t)lrowA*Ww + cs0 + 4*lq;
    const float* gsrcB = x + (size_t)b*Cc*HW + (size_t)lrowB*Ww + cs0 + 4*lq;

    float* winw = lWin + grp*1024;    // this wave's 2 x 512-float buffers

#define ISSUE(gs, q) { \
    _Pragma("unroll") \
    for (int p = 0; p < 2; ++p) \
        gload_lds16((gs) + (size_t)(grp*32 + (q)*4 + p*2 + chsub)*HW, \
                    winw + ((q)&1)*512 + p*256); }

// r12's pipeline, verbatim, parameterized by tile
#define PRODUCE(gs, W00, W01, W10, W11) { \
    ISSUE(gs, 0) \
    ISSUE(gs, 1) \
    _Pragma("unroll") \
    for (int q = 0; q < 8; ++q) { \
        if (q < 7) asm volatile("s_waitcnt vmcnt(2)" ::: "memory"); \
        else       asm volatile("s_waitcnt vmcnt(0)" ::: "memory"); \
        __builtin_amdgcn_sched_barrier(0); \
        { \
            const float* wb = winw + (q&1)*512; \
            float f[4]; \
            _Pragma("unroll") \
            for (int u = 0; u < 4; ++u) { \
                const float* wc = wb + (u>>1)*256 + (u&1)*128; \
                f[u] = (W00)*wc[ro0] + (W01)*wc[ro0+1] + (W10)*wc[ro1] + (W11)*wc[ro1+1]; \
            } \
            uint2 v; \
            v.x = f2bf(f[0]) | (f2bf(f[1]) << 16); \
            v.y = f2bf(f[2]) | (f2bf(f[3]) << 16); \
            const int c = grp*32 + q*4; \
            int byte = xl*256 + c*2; \
            byte ^= (xl & 7) << 4; \
            *reinterpret_cast<uint2*>(reinterpret_cast<char*>(lF) + byte) = v; \
        } \
        if (q < 6) { \
            asm volatile("s_waitcnt lgkmcnt(0)" ::: "memory"); \
            __builtin_amdgcn_sched_barrier(0); \
            ISSUE(gs, q+2) \
        } \
    } }

#define GEMM_STORE(J0) { \
    f32x4 acc[2][4]; \
    _Pragma("unroll") \
    for (int t = 0; t < 2; ++t) \
        _Pragma("unroll") \
        for (int nn = 0; nn < 4; ++nn) acc[t][nn] = (f32x4){0.f, 0.f, 0.f, 0.f}; \
    _Pragma("unroll") \
    for (int kk = 0; kk < 4; ++kk) { \
        _Pragma("unroll") \
        for (int nn = 0; nn < 4; ++nn) { \
            int byte = (nn*16 + lo)*256 + kk*64 + hi*16; \
            byte ^= (lo & 7) << 4; \
            const s16x8 bf = *reinterpret_cast<const s16x8*>( \
                reinterpret_cast<const char*>(lF) + byte); \
            acc[0][nn] = __builtin_amdgcn_mfma_f32_16x16x32_bf16(a[0][kk], bf, acc[0][nn], 0, 0, 0); \
            acc[1][nn] = __builtin_amdgcn_mfma_f32_16x16x32_bf16(a[1][kk], bf, acc[1][nn], 0, 0, 0); \
        } \
    } \
    _Pragma("unroll") \
    for (int t = 0; t < 2; ++t) \
        _Pragma("unroll") \
        for (int nn = 0; nn < 4; ++nn) { \
            const int slot2 = nn*16 + lo; \
            const int pr2 = slot2 >> 5, pc2 = slot2 & 31; \
            const int yg = 2*((J0) + pr2) + py; \
            const int xg = 2*(i0 + pc2) + px_; \
            const int ch0 = 32*grp + 16*t + hi*4; \
            float* op = out + ((size_t)(b*Cc + ch0)*H2c + yg)*W2c + xg; \
            _Pragma("unroll") \
            for (int r = 0; r < 4; ++r) \
                op[(size_t)r*HW2] = acc[t][nn][r]; \
        } }

    // ---- tile A ----
    PRODUCE(gsrcA, w00A, w01A, w10A, w11A)
    __syncthreads();
    GEMM_STORE(j0A)
    __syncthreads();          // lF reads done before tile B overwrites

    // ---- tile B ----
    PRODUCE(gsrcB, w00B, w01B, w10B, w11B)
    __syncthreads();
    GEMM_STORE(j0B)

#undef ISSUE
#undef PRODUCE
#undef GEMM_STORE
}

extern "C" void kernel_launch(void* const* d_in, const int* in_sizes, int n_in,
                              void* d_out, int out_size, void* d_ws, size_t ws_size,
                              hipStream_t stream) {
    const float* x     = (const float*)d_in[0];
    const float* wcomp = (const float*)d_in[1];
    const float* wexp  = (const float*)d_in[2];
    const float* bw1   = (const float*)d_in[3];
    const float* bb1   = (const float*)d_in[4];
    const float* bw2   = (const float*)d_in[5];
    const float* bb2   = (const float*)d_in[6];
    const float* rw    = (const float*)d_in[7];
    const float* rb    = (const float*)d_in[8];
    const float* ow    = (const float*)d_in[9];
    const float* ob    = (const float*)d_in[10];
    float* out = (float*)d_out;
    float* ws  = (float*)d_ws;
    unsigned short* Mw = (unsigned short*)(ws + M_OFF);   // ~128 KB used

    k1_prep<<<64, 256, 0, stream>>>(wcomp, wexp, bw1, bb1, bw2, bb2,
                                    rw, rb, ow, ob, ws, Mw);
    k2_mfma<<<1152, 256, 0, stream>>>(x, ws, Mw, out);
}